// Round 5
// baseline (26.390 us; speedup 1.0000x reference)
//
#include <hip/hip_runtime.h>

#define NUM_CLASSES 6625
#define FEAT_DIM 96
#define NROWS 4096
#define CLAMP_MIN 1e-12
#define CLAMP_MAX 1e12

// One WAVE per row, 4 independent waves per 256-thread block. No LDS, no
// barriers, no atomics. Per lane: 26 float4 loads in 4 batches feeding 8
// independent compare chains (within-chain element indices are monotonically
// increasing, so strict '>' keeps the first occurrence == jnp.argmax).
// Then wave shuffle reduce, fused f64 squared distance, store per-row double.
__global__ __launch_bounds__(256) void argmax_dist_kernel(
    const float* __restrict__ pred,
    const float* __restrict__ feats,
    const float* __restrict__ centers,
    double* __restrict__ dists)
{
    const int C = NUM_CLASSES;
    const int lane = threadIdx.x & 63;
    const int row  = blockIdx.x * 4 + (threadIdx.x >> 6);
    const float* p = pred + (size_t)row * C;

    // Row base element offset is row*6625 ≡ row (mod 4): scalar prefix to
    // reach 16B alignment for float4 loads.
    const int prefix = (4 - (row & 3)) & 3;
    const int nvec = (C - prefix) >> 2;              // 1655 or 1656
    const float4* pv = (const float4*)(p + prefix);

    float b0, b1, b2, b3, b4, b5, b6, b7;
    int   j0, j1, j2, j3, j4, j5, j6, j7;
    b0=b1=b2=b3=b4=b5=b6=b7 = -__builtin_inff();
    j0=j1=j2=j3=j4=j5=j6=j7 = C;

    // Prefix scalars (element indices 0..prefix-1, smaller than everything
    // chain 0 sees later).
    if (lane < prefix) { b0 = p[lane]; j0 = lane; }

    #define CHAIN(vv, bb, jj, vecidx) { \
        const int e = prefix + 4 * (vecidx); \
        if (vv.x > bb) { bb = vv.x; jj = e; } \
        if (vv.y > bb) { bb = vv.y; jj = e + 1; } \
        if (vv.z > bb) { bb = vv.z; jj = e + 2; } \
        if (vv.w > bb) { bb = vv.w; jj = e + 3; } }

    // Batches of 8: chain c takes vec index lane + 64*(batch*8 + c).
    // k = 0..23 always valid: max vec idx = 63 + 64*23 = 1535 < 1655.
    #pragma unroll
    for (int bat = 0; bat < 3; ++bat) {
        const int base = lane + 512 * bat;
        float4 w0 = pv[base];
        float4 w1 = pv[base +  64];
        float4 w2 = pv[base + 128];
        float4 w3 = pv[base + 192];
        float4 w4 = pv[base + 256];
        float4 w5 = pv[base + 320];
        float4 w6 = pv[base + 384];
        float4 w7 = pv[base + 448];
        CHAIN(w0, b0, j0, base)
        CHAIN(w1, b1, j1, base +  64)
        CHAIN(w2, b2, j2, base + 128)
        CHAIN(w3, b3, j3, base + 192)
        CHAIN(w4, b4, j4, base + 256)
        CHAIN(w5, b5, j5, base + 320)
        CHAIN(w6, b6, j6, base + 384)
        CHAIN(w7, b7, j7, base + 448)
    }
    // Tail batch: k=24 (always valid: 1536+63=1599<1655) -> chain 0;
    // k=25 (vec idx 1600+lane, valid for lane<nvec-1600) -> chain 1.
    {
        const int i24 = lane + 1536;
        float4 w0 = pv[i24];
        const int i25 = lane + 1600;
        const bool v25 = i25 < nvec;
        float4 w1 = pv[v25 ? i25 : (nvec - 1)];      // clamped, unconditional
        CHAIN(w0, b0, j0, i24)
        if (v25) CHAIN(w1, b1, j1, i25)
    }
    #undef CHAIN

    // Scalar tail (largest element indices) -> chain 7 (its max index is
    // prefix + 4*(63 + 64*23) + 3 < 6150 < tailstart).
    {
        const int tailstart = prefix + 4 * nvec;
        const int tails = C - tailstart;             // 0..3
        if (lane < tails) {
            const float v = p[tailstart + lane];
            if (v > b7) { b7 = v; j7 = tailstart + lane; }
        }
    }

    // Merge chains (value desc, index asc on tie).
    float best = b0; int bidx = j0;
    #define MERGE(bb, jj) if (bb > best || (bb == best && jj < bidx)) { best = bb; bidx = jj; }
    MERGE(b1, j1) MERGE(b2, j2) MERGE(b3, j3)
    MERGE(b4, j4) MERGE(b5, j5) MERGE(b6, j6) MERGE(b7, j7)
    #undef MERGE

    // Wave shuffle reduce (64 lanes), no barrier.
    for (int off = 32; off > 0; off >>= 1) {
        float ov = __shfl_down(best, off, 64);
        int   oi = __shfl_down(bidx, off, 64);
        if (ov > best || (ov == best && oi < bidx)) { best = ov; bidx = oi; }
    }
    const int label = __shfl(bidx, 0, 64);

    // f64 squared distance: lane handles element lane (+ lane+64 if lane<32).
    const float* frow = feats + row * FEAT_DIM;
    const float* crow = centers + (size_t)label * FEAT_DIM;
    double d0 = (double)frow[lane] - (double)crow[lane];
    double acc = d0 * d0;
    if (lane < 32) {
        double d1 = (double)frow[lane + 64] - (double)crow[lane + 64];
        acc += d1 * d1;
    }
    for (int off = 32; off > 0; off >>= 1)
        acc += __shfl_down(acc, off, 64);
    if (lane == 0) {
        double dn = acc;
        dn = dn < CLAMP_MIN ? CLAMP_MIN : (dn > CLAMP_MAX ? CLAMP_MAX : dn);
        dists[row] = dn;
    }
}

// Single-block final reduction: mean over rows + the (C-1)*1e-12 constant from
// the reference's clip-after-mask on the zeroed columns.
__global__ __launch_bounds__(256) void reduce_kernel(
    const double* __restrict__ dists, float* __restrict__ out)
{
    const int tid = threadIdx.x;
    double s = 0.0;
    #pragma unroll
    for (int i = 0; i < NROWS / 256; ++i) s += dists[tid + i * 256];
    for (int off = 32; off > 0; off >>= 1)
        s += __shfl_down(s, off, 64);
    __shared__ double sw[4];
    const int wave = tid >> 6;
    const int lane = tid & 63;
    if (lane == 0) sw[wave] = s;
    __syncthreads();
    if (tid == 0) {
        double t = sw[0] + sw[1] + sw[2] + sw[3];
        out[0] = (float)(t / (double)NROWS
                         + (double)(NUM_CLASSES - 1) * CLAMP_MIN);
    }
}

extern "C" void kernel_launch(void* const* d_in, const int* in_sizes, int n_in,
                              void* d_out, int out_size, void* d_ws, size_t ws_size,
                              hipStream_t stream) {
    const float* feats   = (const float*)d_in[0];  // [4096, 96]
    const float* pred    = (const float*)d_in[1];  // [4096, 6625]
    const float* centers = (const float*)d_in[2];  // [6625, 96]
    double* dists = (double*)d_ws;                 // 4096 * 8 B = 32 KiB
    float* out = (float*)d_out;

    argmax_dist_kernel<<<NROWS / 4, 256, 0, stream>>>(pred, feats, centers, dists);
    reduce_kernel<<<1, 256, 0, stream>>>(dists, out);
}

// Round 6
// 23.770 us; speedup vs baseline: 1.1102x; 1.1102x over previous
//
#include <hip/hip_runtime.h>

#define NUM_CLASSES 6625
#define FEAT_DIM 96
#define NROWS 4096
#define CLAMP_MIN 1e-12
#define CLAMP_MAX 1e12

// clang ext_vector type so __builtin_nontemporal_load works (HIP's float4 is
// a struct, not a vector type).
typedef float vfloat4 __attribute__((ext_vector_type(4)));

// One 256-thread block per row (R4 structure, best measured). Each thread
// issues all 7 of its float4 loads up front as NON-TEMPORAL (pure stream, no
// reuse -> bypass L2 allocation), compares into 7 independent chains
// (within-chain element indices increase monotonically, so strict '>' keeps
// the first occurrence == jnp.argmax), then wave shuffle reduce + one LDS
// merge. Wave 0 computes the fused f64 squared distance to centers[label].
__global__ __launch_bounds__(256) void argmax_dist_kernel(
    const float* __restrict__ pred,
    const float* __restrict__ feats,
    const float* __restrict__ centers,
    double* __restrict__ dists)
{
    const int C = NUM_CLASSES;
    const int row = blockIdx.x;
    const int tid = threadIdx.x;
    const float* p = pred + (size_t)row * C;

    // Row base element offset is row*6625 ≡ row (mod 4): scalar prefix to
    // reach 16B alignment for float4 loads.
    const int prefix = (4 - (row & 3)) & 3;
    const int nvec = (C - prefix) >> 2;              // 1655 or 1656
    const vfloat4* pv = (const vfloat4*)(p + prefix);

    // ---- Issue every load this thread needs, back to back (nt). ----
    vfloat4 v0 = __builtin_nontemporal_load(pv + tid);
    vfloat4 v1 = __builtin_nontemporal_load(pv + tid + 256);
    vfloat4 v2 = __builtin_nontemporal_load(pv + tid + 512);
    vfloat4 v3 = __builtin_nontemporal_load(pv + tid + 768);
    vfloat4 v4 = __builtin_nontemporal_load(pv + tid + 1024);
    vfloat4 v5 = __builtin_nontemporal_load(pv + tid + 1280);
    const int i6 = tid + 1536;
    const bool val6 = i6 < nvec;
    vfloat4 v6 = __builtin_nontemporal_load(pv + (val6 ? i6 : (nvec - 1)));
    // Prefix scalar (element indices 0..prefix-1, the smallest).
    const bool valp = tid < prefix;
    float vp = p[valp ? tid : 0];
    // Tail scalars (largest element indices: tailstart..C-1).
    const int tailstart = prefix + 4 * nvec;
    const bool valt = tid < (C - tailstart);
    float vt = p[valt ? (tailstart + tid) : 0];

    // ---- Compare phase. ----
    float b0, b1, b2, b3, b4, b5, b6;
    int   j0, j1, j2, j3, j4, j5, j6;
    b0=b1=b2=b3=b4=b5=b6 = -__builtin_inff();
    j0=j1=j2=j3=j4=j5=j6 = C;

    // Chain 0 starts with the prefix element (index tid < prefix+4*tid).
    if (valp) { b0 = vp; j0 = tid; }

    #define CHAIN(vv, bb, jj, vecidx) { \
        const int e = prefix + 4 * (vecidx); \
        if (vv.x > bb) { bb = vv.x; jj = e; } \
        if (vv.y > bb) { bb = vv.y; jj = e + 1; } \
        if (vv.z > bb) { bb = vv.z; jj = e + 2; } \
        if (vv.w > bb) { bb = vv.w; jj = e + 3; } }
    CHAIN(v0, b0, j0, tid)
    CHAIN(v1, b1, j1, tid + 256)
    CHAIN(v2, b2, j2, tid + 512)
    CHAIN(v3, b3, j3, tid + 768)
    CHAIN(v4, b4, j4, tid + 1024)
    CHAIN(v5, b5, j5, tid + 1280)
    if (val6) CHAIN(v6, b6, j6, i6)
    #undef CHAIN
    // Tail folds into chain 6: its element indices exceed everything there.
    if (valt) {
        const int e = tailstart + tid;
        if (vt > b6) { b6 = vt; j6 = e; }
    }

    // Merge chains (value desc, index asc on tie).
    float best = b0; int bidx = j0;
    #define MERGE(bb, jj) if (bb > best || (bb == best && jj < bidx)) { best = bb; bidx = jj; }
    MERGE(b1, j1) MERGE(b2, j2) MERGE(b3, j3)
    MERGE(b4, j4) MERGE(b5, j5) MERGE(b6, j6)
    #undef MERGE

    // Wave shuffle reduce (64 lanes), no barrier.
    for (int off = 32; off > 0; off >>= 1) {
        float ov = __shfl_down(best, off, 64);
        int   oi = __shfl_down(bidx, off, 64);
        if (ov > best || (ov == best && oi < bidx)) { best = ov; bidx = oi; }
    }

    // Cross-wave merge: 4 partials through LDS, single barrier.
    __shared__ float swv[4];
    __shared__ int   swi[4];
    const int wave = tid >> 6;
    const int lane = tid & 63;
    if (lane == 0) { swv[wave] = best; swi[wave] = bidx; }
    __syncthreads();
    if (tid >= 64) return;

    float bv = swv[0]; int bi = swi[0];
    #pragma unroll
    for (int w = 1; w < 4; ++w) {
        float v2 = swv[w]; int i2 = swi[w];
        if (v2 > bv || (v2 == bv && i2 < bi)) { bv = v2; bi = i2; }
    }
    const int label = bi;  // uniform across wave 0

    // f64 squared distance: lane handles element lane (+ lane+64 if lane<32).
    const float* frow = feats + row * FEAT_DIM;
    const float* crow = centers + (size_t)label * FEAT_DIM;
    double d0 = (double)frow[lane] - (double)crow[lane];
    double acc = d0 * d0;
    if (lane < 32) {
        double d1 = (double)frow[lane + 64] - (double)crow[lane + 64];
        acc += d1 * d1;
    }
    for (int off = 32; off > 0; off >>= 1)
        acc += __shfl_down(acc, off, 64);
    if (lane == 0) {
        double dn = acc;
        dn = dn < CLAMP_MIN ? CLAMP_MIN : (dn > CLAMP_MAX ? CLAMP_MAX : dn);
        dists[row] = dn;
    }
}

// Single-WAVE final reduction: 64 lanes, 4 independent accumulation chains,
// shuffle-only (no LDS, no barriers). Adds the (C-1)*1e-12 constant from the
// reference's clip-after-mask on the zeroed columns.
__global__ __launch_bounds__(64) void reduce_kernel(
    const double* __restrict__ dists, float* __restrict__ out)
{
    const int lane = threadIdx.x;
    double s0 = 0.0, s1 = 0.0, s2 = 0.0, s3 = 0.0;
    #pragma unroll
    for (int k = 0; k < 16; ++k) {
        s0 += dists[lane + 64 * (4 * k + 0)];
        s1 += dists[lane + 64 * (4 * k + 1)];
        s2 += dists[lane + 64 * (4 * k + 2)];
        s3 += dists[lane + 64 * (4 * k + 3)];
    }
    double s = (s0 + s1) + (s2 + s3);
    for (int off = 32; off > 0; off >>= 1)
        s += __shfl_down(s, off, 64);
    if (lane == 0)
        out[0] = (float)(s / (double)NROWS
                         + (double)(NUM_CLASSES - 1) * CLAMP_MIN);
}

extern "C" void kernel_launch(void* const* d_in, const int* in_sizes, int n_in,
                              void* d_out, int out_size, void* d_ws, size_t ws_size,
                              hipStream_t stream) {
    const float* feats   = (const float*)d_in[0];  // [4096, 96]
    const float* pred    = (const float*)d_in[1];  // [4096, 6625]
    const float* centers = (const float*)d_in[2];  // [6625, 96]
    double* dists = (double*)d_ws;                 // 4096 * 8 B = 32 KiB
    float* out = (float*)d_out;

    argmax_dist_kernel<<<NROWS, 256, 0, stream>>>(pred, feats, centers, dists);
    reduce_kernel<<<1, 64, 0, stream>>>(dists, out);
}